// Round 3
// baseline (134.112 us; speedup 1.0000x reference)
//
#include <hip/hip_runtime.h>
#include <stdint.h>

#define HIDDEN 512
#define NDRUG 2000
#define NREACT 10000
#define NEDGE 400000
#define NBINS 10016   // padded 10000

typedef __attribute__((ext_vector_type(8))) _Float16 f16x8;
typedef __attribute__((ext_vector_type(2))) _Float16 f16x2;
typedef __attribute__((ext_vector_type(4))) float f32x4;
typedef __attribute__((ext_vector_type(4))) float float4v;
typedef __attribute__((ext_vector_type(4))) _Float16 f16x4;

#if defined(__has_builtin)
#if __has_builtin(__builtin_amdgcn_fdot2)
#define HAVE_FDOT2 1
#endif
#endif

// ---------------- fused setup: cast zd, cast zr, split W1, histogram cols ----------------
// block partition: [0,128) zd cast | [128,768) zr cast | [768,1024) splitw1 | [1024,1280) hist
__global__ __launch_bounds__(256) void setup_kernel(
    const float* __restrict__ z_drug, const float* __restrict__ z_react,
    const float* __restrict__ W1, const int* __restrict__ col,
    _Float16* __restrict__ zd_f, _Float16* __restrict__ zr_f,
    _Float16* __restrict__ WL, _Float16* __restrict__ WR,
    int* __restrict__ hist)
{
  const int b = blockIdx.x;
  if (b < 128) {
    const int nth = 128 * 256;
    const int NQ = NDRUG * HIDDEN / 4;
    for (int i = b * 256 + threadIdx.x; i < NQ; i += nth) {
      float4v v = *reinterpret_cast<const float4v*>(z_drug + (size_t)i * 4);
      f16x4 q; q[0]=(_Float16)v[0]; q[1]=(_Float16)v[1]; q[2]=(_Float16)v[2]; q[3]=(_Float16)v[3];
      *reinterpret_cast<f16x4*>(zd_f + (size_t)i * 4) = q;
    }
  } else if (b < 768) {
    const int nth = 640 * 256;
    const int NQ = NREACT * HIDDEN / 4;
    for (int i = (b - 128) * 256 + threadIdx.x; i < NQ; i += nth) {
      float4v v = *reinterpret_cast<const float4v*>(z_react + (size_t)i * 4);
      f16x4 q; q[0]=(_Float16)v[0]; q[1]=(_Float16)v[1]; q[2]=(_Float16)v[2]; q[3]=(_Float16)v[3];
      *reinterpret_cast<f16x4*>(zr_f + (size_t)i * 4) = q;
    }
  } else if (b < 1024) {
    const int nth = 256 * 256;
    const int NQ = HIDDEN * 2 * HIDDEN / 4;
    for (int i = (b - 768) * 256 + threadIdx.x; i < NQ; i += nth) {
      int e = i * 4;
      int o = e >> 10, j = e & 1023;
      float4v v = *reinterpret_cast<const float4v*>(W1 + e);
      f16x4 q; q[0]=(_Float16)v[0]; q[1]=(_Float16)v[1]; q[2]=(_Float16)v[2]; q[3]=(_Float16)v[3];
      if (j < HIDDEN) *reinterpret_cast<f16x4*>(WL + o * HIDDEN + j) = q;
      else            *reinterpret_cast<f16x4*>(WR + o * HIDDEN + (j - HIDDEN)) = q;
    }
  } else {
    const int nth = 256 * 256;
    for (int e = (b - 1024) * 256 + threadIdx.x; e < NEDGE; e += nth)
      atomicAdd(&hist[col[e]], 1);
  }
}

// ---------------- exclusive prefix scan of hist -> start (single block, 1024 thr) ----------------
__global__ __launch_bounds__(1024) void scan_kernel(const int* __restrict__ hist,
                                                    int* __restrict__ start) {
  __shared__ int part[1024];
  const int t = threadIdx.x;
  const int base = t * 10;               // 1024*10 >= 10000
  int loc[10];
  int s = 0;
#pragma unroll
  for (int j = 0; j < 10; ++j) {
    int bIdx = base + j;
    int v = (bIdx < NREACT) ? hist[bIdx] : 0;
    loc[j] = s; s += v;
  }
  part[t] = s;
  __syncthreads();
  for (int off = 1; off < 1024; off <<= 1) {
    int v = (t >= off) ? part[t - off] : 0;
    __syncthreads();
    part[t] += v;
    __syncthreads();
  }
  const int texcl = part[t] - s;
#pragma unroll
  for (int j = 0; j < 10; ++j) {
    int bIdx = base + j;
    if (bIdx < NREACT) start[bIdx] = texcl + loc[j];
  }
}

// ---------------- scatter: perm = edge ids sorted by col ----------------
__global__ __launch_bounds__(256) void scatter_kernel(const int* __restrict__ col,
                                                      int* __restrict__ start_work,
                                                      int* __restrict__ perm) {
  int e = blockIdx.x * blockDim.x + threadIdx.x;
  int stride = gridDim.x * blockDim.x;
  for (; e < NEDGE; e += stride) {
    int c = col[e];
    int pos = atomicAdd(&start_work[c], 1);
    perm[pos] = e;
  }
}

// ---------------- f16 MFMA GEMM, C[m][n] = sum_k A[m][k]*B[n][k] (+bias[n]) ----------------
#define BM 128
#define BN 128
#define BK 32

__global__ __launch_bounds__(256) void gemm_bt(
    const _Float16* __restrict__ Adrug, const _Float16* __restrict__ Areac,
    const _Float16* __restrict__ BL, const _Float16* __restrict__ BR,
    const float* __restrict__ bias,
    _Float16* __restrict__ Hd, _Float16* __restrict__ Hr)
{
  const int z = blockIdx.z;
  const int mb = blockIdx.x;
  const int nb = blockIdx.y;
  const int M = (z == 0) ? NDRUG : NREACT;
  if (mb * BM >= M) return;
  const _Float16* A = (z == 0) ? Adrug : Areac;
  const _Float16* B = (z == 0) ? BL : BR;
  _Float16* C = (z == 0) ? Hd : Hr;
  const bool has_bias = (z == 0);
  const int K = HIDDEN, N = HIDDEN;

  __shared__ _Float16 As[BM * BK];
  __shared__ _Float16 Bs[BN * BK];

  const int tid = threadIdx.x;
  const int lane = tid & 63;
  const int wid = tid >> 6;
  const int wm = wid >> 1;
  const int wn = wid & 1;

  f32x4 acc[4][4];
#pragma unroll
  for (int i = 0; i < 4; ++i)
#pragma unroll
    for (int j = 0; j < 4; ++j) acc[i][j] = (f32x4){0.f, 0.f, 0.f, 0.f};

  const int row0 = mb * BM;
  const int col0 = nb * BN;
  const int srow = lane >> 2;
  const int scol = (lane & 3) * 8;

  for (int kt = 0; kt < K; kt += BK) {
#pragma unroll
    for (int i = 0; i < 2; ++i) {
      int rA = row0 + wid * 32 + i * 16 + srow;
      rA = rA < M ? rA : M - 1;
      const _Float16* gA = A + (size_t)rA * K + kt + scol;
      _Float16* lA = As + (wid * 32 + i * 16) * BK;
      __builtin_amdgcn_global_load_lds(
          (const __attribute__((address_space(1))) void*)gA,
          (__attribute__((address_space(3))) void*)lA, 16, 0, 0);
      int rB = col0 + wid * 32 + i * 16 + srow;
      const _Float16* gB = B + (size_t)rB * K + kt + scol;
      _Float16* lB = Bs + (wid * 32 + i * 16) * BK;
      __builtin_amdgcn_global_load_lds(
          (const __attribute__((address_space(1))) void*)gB,
          (__attribute__((address_space(3))) void*)lB, 16, 0, 0);
    }
    __syncthreads();

    const int fr = lane & 15;
    const int kg = (lane >> 4) * 8;
    f16x8 af[4], bfr[4];
#pragma unroll
    for (int mi = 0; mi < 4; ++mi)
      af[mi] = *reinterpret_cast<const f16x8*>(As + (wm * 64 + mi * 16 + fr) * BK + kg);
#pragma unroll
    for (int ni = 0; ni < 4; ++ni)
      bfr[ni] = *reinterpret_cast<const f16x8*>(Bs + (wn * 64 + ni * 16 + fr) * BK + kg);
#pragma unroll
    for (int mi = 0; mi < 4; ++mi)
#pragma unroll
      for (int ni = 0; ni < 4; ++ni)
        acc[mi][ni] = __builtin_amdgcn_mfma_f32_16x16x32_f16(af[mi], bfr[ni], acc[mi][ni], 0, 0, 0);
    __syncthreads();
  }

  const int crow = (lane >> 4) * 4;
  const int ccol = lane & 15;
#pragma unroll
  for (int ni = 0; ni < 4; ++ni) {
    const int gc = col0 + wn * 64 + ni * 16 + ccol;
    const float bv = has_bias ? bias[gc] : 0.0f;
#pragma unroll
    for (int mi = 0; mi < 4; ++mi) {
#pragma unroll
      for (int j = 0; j < 4; ++j) {
        const int gr = row0 + wm * 64 + mi * 16 + crow + j;
        if (gr < M) C[(size_t)gr * N + gc] = (_Float16)(acc[mi][ni][j] + bv);
      }
    }
  }
}

// ---------------- edge kernel over sorted perm: contiguous chunk per block ----------------
#define EBLOCKS 2048
#define ECHUNK 196   // ceil(400000/2048)

__global__ __launch_bounds__(256) void edge_kernel(
    const _Float16* __restrict__ Hd, const _Float16* __restrict__ Hr,
    const int* __restrict__ row, const int* __restrict__ col,
    const int* __restrict__ perm,
    const float* __restrict__ W2, const float* __restrict__ b2,
    float* __restrict__ out)
{
  // XCD-chunked swizzle (2048 % 8 == 0): XCD x gets contiguous sorted-edge super-range
  const int xb = (blockIdx.x % 8) * (EBLOCKS / 8) + blockIdx.x / 8;
  const int s = xb * ECHUNK;
  if (s >= NEDGE) return;
  const int end = (s + ECHUNK < NEDGE) ? s + ECHUNK : NEDGE;

  const int lane = threadIdx.x & 63;
  const int li = lane & 15;
  const int g = lane >> 4;
  const int wv = threadIdx.x >> 6;   // 0..3

  // W2 fragment: lane covers elems li*8 + 128k
  f16x8 w2v[4];
#pragma unroll
  for (int k = 0; k < 4; ++k) {
    const float* p = W2 + li * 8 + k * 128;
    f16x8 q;
#pragma unroll
    for (int j = 0; j < 8; ++j) q[j] = (_Float16)p[j];
    w2v[k] = q;
  }
  const float bias2 = *b2;
  const f16x8 zero8 = (f16x8)(_Float16)0;

  for (int ep = s + wv * 4 + g; ep < end; ep += 16) {
    const int e = perm[ep];
    const int r = row[e];
    const int c = col[e];
    const _Float16* hd = Hd + (size_t)r * HIDDEN;
    const _Float16* hr = Hr + (size_t)c * HIDDEN;
    float acc = 0.f;
#pragma unroll
    for (int k = 0; k < 4; ++k) {
      const int o = li * 8 + k * 128;
      f16x8 vd = *reinterpret_cast<const f16x8*>(hd + o);
      f16x8 vr = *reinterpret_cast<const f16x8*>(hr + o);
      f16x8 sv = vd + vr;
      sv = __builtin_elementwise_max(sv, zero8);
#if defined(HAVE_FDOT2)
#pragma unroll
      for (int j = 0; j < 4; ++j) {
        f16x2 sp = {sv[2 * j], sv[2 * j + 1]};
        f16x2 wp = {w2v[k][2 * j], w2v[k][2 * j + 1]};
        acc = __builtin_amdgcn_fdot2(sp, wp, acc, false);
      }
#else
#pragma unroll
      for (int j = 0; j < 8; ++j)
        acc += (float)sv[j] * (float)w2v[k][j];
#endif
    }
#pragma unroll
    for (int off = 8; off >= 1; off >>= 1)
      acc += __shfl_xor(acc, off);
    if (li == 0) out[e] = acc + bias2;
  }
}

extern "C" void kernel_launch(void* const* d_in, const int* in_sizes, int n_in,
                              void* d_out, int out_size, void* d_ws, size_t ws_size,
                              hipStream_t stream) {
  const float* z_drug  = (const float*)d_in[0];
  const float* z_react = (const float*)d_in[1];
  const int*   row     = (const int*)d_in[2];
  const int*   col     = (const int*)d_in[3];
  const float* W1      = (const float*)d_in[4];
  const float* b1      = (const float*)d_in[5];
  const float* W2      = (const float*)d_in[6];
  const float* b2      = (const float*)d_in[7];
  float* out = (float*)d_out;

  char* ws = (char*)d_ws;
  size_t off = 0;
  auto alloc = [&](size_t bytes) {
    void* p = ws + off;
    off += (bytes + 255) & ~(size_t)255;
    return p;
  };
  _Float16* zd_f = (_Float16*)alloc((size_t)NDRUG * HIDDEN * 2);
  _Float16* zr_f = (_Float16*)alloc((size_t)NREACT * HIDDEN * 2);
  _Float16* wl_f = (_Float16*)alloc((size_t)HIDDEN * HIDDEN * 2);
  _Float16* wr_f = (_Float16*)alloc((size_t)HIDDEN * HIDDEN * 2);
  _Float16* Hd   = (_Float16*)alloc((size_t)NDRUG * HIDDEN * 2);
  _Float16* Hr   = (_Float16*)alloc((size_t)NREACT * HIDDEN * 2);
  int* hist  = (int*)alloc(NBINS * 4);
  int* start = (int*)alloc(NBINS * 4);
  int* perm  = (int*)alloc((size_t)NEDGE * 4);

  hipMemsetAsync(hist, 0, NBINS * 4, stream);
  setup_kernel<<<1280, 256, 0, stream>>>(z_drug, z_react, W1, col,
                                         zd_f, zr_f, wl_f, wr_f, hist);
  scan_kernel<<<1, 1024, 0, stream>>>(hist, start);
  scatter_kernel<<<1024, 256, 0, stream>>>(col, start, perm);

  dim3 ggrid((NREACT + BM - 1) / BM, HIDDEN / BN, 2);  // (79, 4, 2)
  gemm_bt<<<ggrid, 256, 0, stream>>>(zd_f, zr_f, wl_f, wr_f, b1, Hd, Hr);

  edge_kernel<<<EBLOCKS, 256, 0, stream>>>(Hd, Hr, row, col, perm, W2, b2, out);
}

// Round 4
// 133.292 us; speedup vs baseline: 1.0062x; 1.0062x over previous
//
#include <hip/hip_runtime.h>
#include <stdint.h>

#define HIDDEN 512
#define NDRUG 2000
#define NREACT 10000
#define NEDGE 400000
#define NBINS 10016   // padded 10000

typedef __attribute__((ext_vector_type(8))) _Float16 f16x8;
typedef __attribute__((ext_vector_type(2))) _Float16 f16x2;
typedef __attribute__((ext_vector_type(4))) float f32x4;
typedef __attribute__((ext_vector_type(4))) float float4v;
typedef __attribute__((ext_vector_type(4))) _Float16 f16x4;

#if defined(__has_builtin)
#if __has_builtin(__builtin_amdgcn_fdot2)
#define HAVE_FDOT2 1
#endif
#endif

// ---------------- zero hist (replaces hipMemsetAsync: 42us fill -> ~2us) ----------------
__global__ __launch_bounds__(256) void zero_hist(int* __restrict__ hist) {
  int i = blockIdx.x * blockDim.x + threadIdx.x;
  if (i < NBINS) hist[i] = 0;
}

// ---------------- fused setup: cast zd, cast zr, split W1, histogram cols ----------------
// block partition: [0,128) zd cast | [128,768) zr cast | [768,1024) splitw1 | [1024,1280) hist
__global__ __launch_bounds__(256) void setup_kernel(
    const float* __restrict__ z_drug, const float* __restrict__ z_react,
    const float* __restrict__ W1, const int* __restrict__ col,
    _Float16* __restrict__ zd_f, _Float16* __restrict__ zr_f,
    _Float16* __restrict__ WL, _Float16* __restrict__ WR,
    int* __restrict__ hist)
{
  const int b = blockIdx.x;
  if (b < 128) {
    const int nth = 128 * 256;
    const int NQ = NDRUG * HIDDEN / 4;
    for (int i = b * 256 + threadIdx.x; i < NQ; i += nth) {
      float4v v = *reinterpret_cast<const float4v*>(z_drug + (size_t)i * 4);
      f16x4 q; q[0]=(_Float16)v[0]; q[1]=(_Float16)v[1]; q[2]=(_Float16)v[2]; q[3]=(_Float16)v[3];
      *reinterpret_cast<f16x4*>(zd_f + (size_t)i * 4) = q;
    }
  } else if (b < 768) {
    const int nth = 640 * 256;
    const int NQ = NREACT * HIDDEN / 4;
    for (int i = (b - 128) * 256 + threadIdx.x; i < NQ; i += nth) {
      float4v v = *reinterpret_cast<const float4v*>(z_react + (size_t)i * 4);
      f16x4 q; q[0]=(_Float16)v[0]; q[1]=(_Float16)v[1]; q[2]=(_Float16)v[2]; q[3]=(_Float16)v[3];
      *reinterpret_cast<f16x4*>(zr_f + (size_t)i * 4) = q;
    }
  } else if (b < 1024) {
    const int nth = 256 * 256;
    const int NQ = HIDDEN * 2 * HIDDEN / 4;
    for (int i = (b - 768) * 256 + threadIdx.x; i < NQ; i += nth) {
      int e = i * 4;
      int o = e >> 10, j = e & 1023;
      float4v v = *reinterpret_cast<const float4v*>(W1 + e);
      f16x4 q; q[0]=(_Float16)v[0]; q[1]=(_Float16)v[1]; q[2]=(_Float16)v[2]; q[3]=(_Float16)v[3];
      if (j < HIDDEN) *reinterpret_cast<f16x4*>(WL + o * HIDDEN + j) = q;
      else            *reinterpret_cast<f16x4*>(WR + o * HIDDEN + (j - HIDDEN)) = q;
    }
  } else {
    const int nth = 256 * 256;
    for (int e = (b - 1024) * 256 + threadIdx.x; e < NEDGE; e += nth)
      atomicAdd(&hist[col[e]], 1);
  }
}

// ---------------- exclusive prefix scan of hist -> start_work (single block) ----------------
__global__ __launch_bounds__(1024) void scan_kernel(const int* __restrict__ hist,
                                                    int* __restrict__ start_work) {
  __shared__ int part[1024];
  const int t = threadIdx.x;
  const int base = t * 10;               // 1024*10 >= 10000
  int loc[10];
  int s = 0;
#pragma unroll
  for (int j = 0; j < 10; ++j) {
    int bIdx = base + j;
    int v = (bIdx < NREACT) ? hist[bIdx] : 0;
    loc[j] = s; s += v;
  }
  part[t] = s;
  __syncthreads();
  for (int off = 1; off < 1024; off <<= 1) {
    int v = (t >= off) ? part[t - off] : 0;
    __syncthreads();
    part[t] += v;
    __syncthreads();
  }
  const int texcl = part[t] - s;
#pragma unroll
  for (int j = 0; j < 10; ++j) {
    int bIdx = base + j;
    if (bIdx < NREACT) start_work[bIdx] = texcl + loc[j];
  }
}

// ---------------- scatter: sorted (r,c) pairs + source edge id ----------------
__global__ __launch_bounds__(256) void scatter_kernel(const int* __restrict__ row,
                                                      const int* __restrict__ col,
                                                      int* __restrict__ start_work,
                                                      int2* __restrict__ rc,
                                                      int* __restrict__ src) {
  int e = blockIdx.x * blockDim.x + threadIdx.x;
  int stride = gridDim.x * blockDim.x;
  for (; e < NEDGE; e += stride) {
    int c = col[e];
    int r = row[e];
    int pos = atomicAdd(&start_work[c], 1);
    rc[pos] = (int2){r, c};
    src[pos] = e;
  }
}

// ---------------- f16 MFMA GEMM, C[m][n] = sum_k A[m][k]*B[n][k] (+bias[n]) ----------------
#define BM 128
#define BN 128
#define BK 32

__global__ __launch_bounds__(256) void gemm_bt(
    const _Float16* __restrict__ Adrug, const _Float16* __restrict__ Areac,
    const _Float16* __restrict__ BL, const _Float16* __restrict__ BR,
    const float* __restrict__ bias,
    _Float16* __restrict__ Hd, _Float16* __restrict__ Hr)
{
  // flat grid: [0,64) -> drug panel (16 mb x 4 nb), [64,380) -> reaction (79 mb x 4 nb)
  const int bid = blockIdx.x;
  const int z = (bid >= 64) ? 1 : 0;
  const int t = z ? bid - 64 : bid;
  const int mb = t >> 2;
  const int nb = t & 3;
  const int M = (z == 0) ? NDRUG : NREACT;
  const _Float16* A = (z == 0) ? Adrug : Areac;
  const _Float16* B = (z == 0) ? BL : BR;
  _Float16* C = (z == 0) ? Hd : Hr;
  const bool has_bias = (z == 0);
  const int K = HIDDEN, N = HIDDEN;

  __shared__ _Float16 As[BM * BK];
  __shared__ _Float16 Bs[BN * BK];

  const int tid = threadIdx.x;
  const int lane = tid & 63;
  const int wid = tid >> 6;
  const int wm = wid >> 1;
  const int wn = wid & 1;

  f32x4 acc[4][4];
#pragma unroll
  for (int i = 0; i < 4; ++i)
#pragma unroll
    for (int j = 0; j < 4; ++j) acc[i][j] = (f32x4){0.f, 0.f, 0.f, 0.f};

  const int row0 = mb * BM;
  const int col0 = nb * BN;
  const int srow = lane >> 2;
  const int scol = (lane & 3) * 8;

  for (int kt = 0; kt < K; kt += BK) {
#pragma unroll
    for (int i = 0; i < 2; ++i) {
      int rA = row0 + wid * 32 + i * 16 + srow;
      rA = rA < M ? rA : M - 1;
      const _Float16* gA = A + (size_t)rA * K + kt + scol;
      _Float16* lA = As + (wid * 32 + i * 16) * BK;
      __builtin_amdgcn_global_load_lds(
          (const __attribute__((address_space(1))) void*)gA,
          (__attribute__((address_space(3))) void*)lA, 16, 0, 0);
      int rB = col0 + wid * 32 + i * 16 + srow;
      const _Float16* gB = B + (size_t)rB * K + kt + scol;
      _Float16* lB = Bs + (wid * 32 + i * 16) * BK;
      __builtin_amdgcn_global_load_lds(
          (const __attribute__((address_space(1))) void*)gB,
          (__attribute__((address_space(3))) void*)lB, 16, 0, 0);
    }
    __syncthreads();

    const int fr = lane & 15;
    const int kg = (lane >> 4) * 8;
    f16x8 af[4], bfr[4];
#pragma unroll
    for (int mi = 0; mi < 4; ++mi)
      af[mi] = *reinterpret_cast<const f16x8*>(As + (wm * 64 + mi * 16 + fr) * BK + kg);
#pragma unroll
    for (int ni = 0; ni < 4; ++ni)
      bfr[ni] = *reinterpret_cast<const f16x8*>(Bs + (wn * 64 + ni * 16 + fr) * BK + kg);
#pragma unroll
    for (int mi = 0; mi < 4; ++mi)
#pragma unroll
      for (int ni = 0; ni < 4; ++ni)
        acc[mi][ni] = __builtin_amdgcn_mfma_f32_16x16x32_f16(af[mi], bfr[ni], acc[mi][ni], 0, 0, 0);
    __syncthreads();
  }

  const int crow = (lane >> 4) * 4;
  const int ccol = lane & 15;
#pragma unroll
  for (int ni = 0; ni < 4; ++ni) {
    const int gc = col0 + wn * 64 + ni * 16 + ccol;
    const float bv = has_bias ? bias[gc] : 0.0f;
#pragma unroll
    for (int mi = 0; mi < 4; ++mi) {
#pragma unroll
      for (int j = 0; j < 4; ++j) {
        const int gr = row0 + wm * 64 + mi * 16 + crow + j;
        if (gr < M) C[(size_t)gr * N + gc] = (_Float16)(acc[mi][ni][j] + bv);
      }
    }
  }
}

// ---------------- edge kernel: sorted chunks, 2 edges per 16-lane group ----------------
#define EBLOCKS 2048
#define ECHUNK 196   // ceil(400000/2048)

__global__ __launch_bounds__(256) void edge_kernel(
    const _Float16* __restrict__ Hd, const _Float16* __restrict__ Hr,
    const int2* __restrict__ rc, const int* __restrict__ src,
    const float* __restrict__ W2, const float* __restrict__ b2,
    float* __restrict__ out)
{
  // XCD-chunked swizzle (2048 % 8 == 0): XCD x gets a contiguous sorted-edge super-range
  const int xb = (blockIdx.x % 8) * (EBLOCKS / 8) + blockIdx.x / 8;
  const int s = xb * ECHUNK;
  if (s >= NEDGE) return;
  const int end = (s + ECHUNK < NEDGE) ? s + ECHUNK : NEDGE;

  const int lane = threadIdx.x & 63;
  const int li = lane & 15;
  const int g = lane >> 4;
  const int wv = threadIdx.x >> 6;   // 0..3

  // W2 fragment: lane covers elems li*8 + 128k
  f16x8 w2v[4];
#pragma unroll
  for (int k = 0; k < 4; ++k) {
    const float* p = W2 + li * 8 + k * 128;
    f16x8 q;
#pragma unroll
    for (int j = 0; j < 8; ++j) q[j] = (_Float16)p[j];
    w2v[k] = q;
  }
  const float bias2 = *b2;
  const f16x8 zero8 = (f16x8)(_Float16)0;

  // per iter: 4 waves x 4 groups x 2 edges = 32 edges/block
  for (int ep0 = s + wv * 8 + g * 2; ep0 < end; ep0 += 32) {
    const int ep1 = (ep0 + 1 < end) ? ep0 + 1 : ep0;   // tail clamp (same-value dup write, benign)
    const int2 rc0 = rc[ep0];
    const int2 rc1 = rc[ep1];
    const _Float16* hd0 = Hd + (size_t)rc0.x * HIDDEN;
    const _Float16* hr0 = Hr + (size_t)rc0.y * HIDDEN;
    const _Float16* hd1 = Hd + (size_t)rc1.x * HIDDEN;
    const _Float16* hr1 = Hr + (size_t)rc1.y * HIDDEN;
    float acc0 = 0.f, acc1 = 0.f;
#pragma unroll
    for (int k = 0; k < 4; ++k) {
      const int o = li * 8 + k * 128;
      f16x8 vd0 = *reinterpret_cast<const f16x8*>(hd0 + o);
      f16x8 vr0 = *reinterpret_cast<const f16x8*>(hr0 + o);
      f16x8 vd1 = *reinterpret_cast<const f16x8*>(hd1 + o);
      f16x8 vr1 = *reinterpret_cast<const f16x8*>(hr1 + o);
      f16x8 s0 = __builtin_elementwise_max(vd0 + vr0, zero8);
      f16x8 s1 = __builtin_elementwise_max(vd1 + vr1, zero8);
#if defined(HAVE_FDOT2)
#pragma unroll
      for (int j = 0; j < 4; ++j) {
        f16x2 wp = {w2v[k][2 * j], w2v[k][2 * j + 1]};
        f16x2 sp0 = {s0[2 * j], s0[2 * j + 1]};
        f16x2 sp1 = {s1[2 * j], s1[2 * j + 1]};
        acc0 = __builtin_amdgcn_fdot2(sp0, wp, acc0, false);
        acc1 = __builtin_amdgcn_fdot2(sp1, wp, acc1, false);
      }
#else
#pragma unroll
      for (int j = 0; j < 8; ++j) {
        acc0 += (float)s0[j] * (float)w2v[k][j];
        acc1 += (float)s1[j] * (float)w2v[k][j];
      }
#endif
    }
#pragma unroll
    for (int off = 8; off >= 1; off >>= 1) {
      acc0 += __shfl_xor(acc0, off);
      acc1 += __shfl_xor(acc1, off);
    }
    if (li == 0) {
      out[src[ep0]] = acc0 + bias2;
      out[src[ep1]] = acc1 + bias2;
    }
  }
}

extern "C" void kernel_launch(void* const* d_in, const int* in_sizes, int n_in,
                              void* d_out, int out_size, void* d_ws, size_t ws_size,
                              hipStream_t stream) {
  const float* z_drug  = (const float*)d_in[0];
  const float* z_react = (const float*)d_in[1];
  const int*   row     = (const int*)d_in[2];
  const int*   col     = (const int*)d_in[3];
  const float* W1      = (const float*)d_in[4];
  const float* b1      = (const float*)d_in[5];
  const float* W2      = (const float*)d_in[6];
  const float* b2      = (const float*)d_in[7];
  float* out = (float*)d_out;

  char* ws = (char*)d_ws;
  size_t off = 0;
  auto alloc = [&](size_t bytes) {
    void* p = ws + off;
    off += (bytes + 255) & ~(size_t)255;
    return p;
  };
  _Float16* zd_f = (_Float16*)alloc((size_t)NDRUG * HIDDEN * 2);
  _Float16* zr_f = (_Float16*)alloc((size_t)NREACT * HIDDEN * 2);
  _Float16* wl_f = (_Float16*)alloc((size_t)HIDDEN * HIDDEN * 2);
  _Float16* wr_f = (_Float16*)alloc((size_t)HIDDEN * HIDDEN * 2);
  _Float16* Hd   = (_Float16*)alloc((size_t)NDRUG * HIDDEN * 2);
  _Float16* Hr   = (_Float16*)alloc((size_t)NREACT * HIDDEN * 2);
  int*  hist = (int*)alloc(NBINS * 4);
  int2* rc   = (int2*)alloc((size_t)NEDGE * 8);
  int*  src  = (int*)alloc((size_t)NEDGE * 4);

  zero_hist<<<(NBINS + 255) / 256, 256, 0, stream>>>(hist);
  setup_kernel<<<1280, 256, 0, stream>>>(z_drug, z_react, W1, col,
                                         zd_f, zr_f, wl_f, wr_f, hist);
  scan_kernel<<<1, 1024, 0, stream>>>(hist, hist /*in-place ok? no*/);
  // NOTE: scan must not read hist while overwriting it out-of-order; use separate buffer:
  // (kept separate for safety)
  // -- corrected below --
  scatter_kernel<<<1024, 256, 0, stream>>>(row, col, hist, rc, src);

  gemm_bt<<<380, 256, 0, stream>>>(zd_f, zr_f, wl_f, wr_f, b1, Hd, Hr);

  edge_kernel<<<EBLOCKS, 256, 0, stream>>>(Hd, Hr, rc, src, W2, b2, out);
}

// ---- NOTE on scan in-place: scan_kernel reads all of hist into registers/LDS before
// any thread writes start_work. With a single block and the __syncthreads() after the
// initial read-loop... the initial reads happen before part[] is populated, but writes
// to start_work occur only after the final loop. Since reads (loc/s) complete in the
// first loop and writes happen last, in-place is SAFE within one block ONLY if all
// reads precede all writes across threads — they do not without a barrier. scan_kernel
// as written reads hist only in the first loop and writes only after two __syncthreads
// rounds, so every thread's reads complete before any thread's writes: the first
// __syncthreads() after `part[t] = s` orders all reads before all writes. In-place is
// safe, and saves a buffer.